// Round 1
// baseline (73.943 us; speedup 1.0000x reference)
//
#include <hip/hip_runtime.h>

#define NN 32
#define CC 256
#define KK 8192
#define PARTS 16
#define TPB 256
#define MAX_INIT (-100.0f)

// Kernel 1: blocks 0..31 compute pooled_count[n][p] = sum_k vm[n][k]*(lab[k]==p)
//           block 32 computes patch_count[p] = #k with lab[k]==p
// ws layout (floats): ws[n*16+p] for n in [0,32), ws[32*16 + p] = patch_count[p]
__global__ __launch_bounds__(TPB) void counts_kernel(const int* __restrict__ labels,
                                                     const int* __restrict__ vm,
                                                     float* __restrict__ ws) {
    __shared__ float cnt[PARTS * TPB];
    const int t = threadIdx.x;
    const int b = blockIdx.x;
#pragma unroll
    for (int p = 0; p < PARTS; ++p) cnt[p * TPB + t] = 0.0f;
    __syncthreads();
    if (b < NN) {
        const int base = b * KK;
        for (int k = t; k < KK; k += TPB) {
            int lab = labels[k];
            cnt[lab * TPB + t] += (float)vm[base + k];
        }
    } else {
        for (int k = t; k < KK; k += TPB) {
            int lab = labels[k];
            cnt[lab * TPB + t] += 1.0f;
        }
    }
    __syncthreads();
    for (int s = TPB / 2; s > 0; s >>= 1) {
        if (t < s) {
#pragma unroll
            for (int p = 0; p < PARTS; ++p) cnt[p * TPB + t] += cnt[p * TPB + t + s];
        }
        __syncthreads();
    }
    if (t < PARTS) ws[b * PARTS + t] = cnt[t * TPB];
}

// Kernel 2: one block per (n,c) row. LDS accumulators [part][thread]:
// address p*256+t -> bank t%32 -> 2-way aliasing across wave64 (free).
__global__ __launch_bounds__(TPB) void pool_kernel(const float* __restrict__ feats,
                                                   const int* __restrict__ labels,
                                                   const int* __restrict__ vm,
                                                   const float* __restrict__ ws,
                                                   float* __restrict__ out) {
    __shared__ float ssum[PARTS * TPB];
    __shared__ float smax[PARTS * TPB];
    const int t = threadIdx.x;
    const int b = blockIdx.x;          // b = n*256 + c
    const int n = b >> 8;

#pragma unroll
    for (int p = 0; p < PARTS; ++p) {
        ssum[p * TPB + t] = 0.0f;
        smax[p * TPB + t] = MAX_INIT;
    }
    __syncthreads();

    const float4* __restrict__ frow = (const float4*)(feats + (size_t)b * KK);
    const int4*   __restrict__ lab4 = (const int4*)labels;
    const int4*   __restrict__ vm4  = (const int4*)(vm + (size_t)n * KK);

    for (int i = t; i < KK / 4; i += TPB) {
        float4 f = frow[i];
        int4   l = lab4[i];
        int4   v = vm4[i];
        {
            int a = l.x * TPB + t;
            smax[a] = fmaxf(smax[a], f.x);
            ssum[a] += v.x ? f.x : 0.0f;
        }
        {
            int a = l.y * TPB + t;
            smax[a] = fmaxf(smax[a], f.y);
            ssum[a] += v.y ? f.y : 0.0f;
        }
        {
            int a = l.z * TPB + t;
            smax[a] = fmaxf(smax[a], f.z);
            ssum[a] += v.z ? f.z : 0.0f;
        }
        {
            int a = l.w * TPB + t;
            smax[a] = fmaxf(smax[a], f.w);
            ssum[a] += v.w ? f.w : 0.0f;
        }
    }
    __syncthreads();

    // Reduction: group g (16 threads, j = t&15) owns part g.
    const int g = t >> 4;
    const int j = t & 15;
    float rs = 0.0f;
    float rm = MAX_INIT;
#pragma unroll
    for (int i = 0; i < 16; ++i) {
        rs += ssum[g * TPB + j + 16 * i];
        rm = fmaxf(rm, smax[g * TPB + j + 16 * i]);
    }
#pragma unroll
    for (int m = 8; m >= 1; m >>= 1) {
        rs += __shfl_xor(rs, m, 64);
        rm = fmaxf(rm, __shfl_xor(rm, m, 64));
    }
    if (j == 0) {
        float cntv = ws[n * PARTS + g];
        float pcv  = ws[NN * PARTS + g];
        float mean = rs / fmaxf(cntv, 1.0f);
        float mx   = (pcv > 0.0f) ? rm : 0.0f;
        out[(size_t)b * PARTS + g] = mean + mx;
    }
}

extern "C" void kernel_launch(void* const* d_in, const int* in_sizes, int n_in,
                              void* d_out, int out_size, void* d_ws, size_t ws_size,
                              hipStream_t stream) {
    const float* feats  = (const float*)d_in[0];
    const int*   labels = (const int*)d_in[1];
    const int*   vm     = (const int*)d_in[2];
    float* out = (float*)d_out;
    float* ws  = (float*)d_ws;

    counts_kernel<<<NN + 1, TPB, 0, stream>>>(labels, vm, ws);
    pool_kernel<<<NN * CC, TPB, 0, stream>>>(feats, labels, vm, ws, out);
}